// Round 3
// baseline (183.873 us; speedup 1.0000x reference)
//
#include <hip/hip_runtime.h>
#include <cstdint>

#define DEVI __device__ __forceinline__

using fx4 = __attribute__((ext_vector_type(4))) float;
using bf8 = __attribute__((ext_vector_type(8))) __bf16;
using s8v = __attribute__((ext_vector_type(8))) short;
using s4v = __attribute__((ext_vector_type(4))) short;
typedef unsigned short u16;
typedef unsigned int u32;

DEVI float b2f(u16 u) { return __builtin_bit_cast(float, (u32)u << 16); }
DEVI u16 f2b(float f) {
  u32 u = __builtin_bit_cast(u32, f);
  return (u16)((u + 0x7fffu + ((u >> 16) & 1u)) >> 16);
}

// async global->LDS, 16B per lane, dest = wave-uniform base + lane*16
#define GLOAD(g, l)                                                          \
  __builtin_amdgcn_global_load_lds(                                          \
      (const __attribute__((address_space(1))) unsigned int*)(g),            \
      (__attribute__((address_space(3))) unsigned int*)(l), 16, 0, 0)

// ---- weight prep: W0->bf16, Wqk2=[Wq|Wq ; Wk|Wk] bf16, WvT bf16 ----
__global__ __launch_bounds__(256) void prep(const float* __restrict__ W0,
                                            const float* __restrict__ Wq,
                                            const float* __restrict__ Wk,
                                            const float* __restrict__ Wv,
                                            u16* __restrict__ w0b,
                                            u16* __restrict__ wqk2,
                                            u16* __restrict__ wvtb) {
  const int i = blockIdx.x * 256 + threadIdx.x;
  if (blockIdx.y == 0) {
    if (i < 131072) w0b[i] = f2b(W0[i]);
  } else if (blockIdx.y == 1) {
    if (i < 524288) {
      const int row = i >> 9, c = i & 511;
      const float* src = (row < 256) ? Wq : Wk;
      wqk2[i] = f2b(src[((row & 255) << 8) + (c & 255)]);
    }
  } else {
    if (i < 65536) {
      const int e = i >> 8, d = i & 255;
      wvtb[i] = f2b(Wv[d * 256 + e]);   // WvT[e,d] = Wv[d,e]
    }
  }
}

// ---- Wc = Wsp @ Wp (bf16), bc = Wsp @ bp (fp32) ----
__global__ __launch_bounds__(256) void wcmul(const float* __restrict__ Wsp,
                                             const float* __restrict__ Wp,
                                             const float* __restrict__ bp,
                                             u16* __restrict__ wcb, float* __restrict__ bc) {
  const int o = blockIdx.x, t = threadIdx.x;
  __shared__ float row[256];
  __shared__ float red[4];
  row[t] = Wsp[o * 256 + t];
  __syncthreads();
  float acc = 0.f;
  for (int c = 0; c < 256; ++c) acc += row[c] * Wp[c * 256 + t];
  wcb[o * 256 + t] = f2b(acc);
  float pb = row[t] * bp[t];
#pragma unroll
  for (int m = 32; m > 0; m >>= 1) pb += __shfl_xor(pb, m);
  if ((t & 63) == 0) red[t >> 6] = pb;
  __syncthreads();
  if (t == 0) bc[o] = red[0] + red[1] + red[2] + red[3];
}

// ---- concat + transpose: fd,fs [B,C,N] fp32 -> cat_t [B,N,2C] bf16 ----
__global__ void pack_cat(const float* __restrict__ fd, const float* __restrict__ fs,
                         u16* __restrict__ out) {
  __shared__ float t[32][33];
  const int b = blockIdx.z;
  const int n0 = blockIdx.x * 32;
  const int g = blockIdx.y;
  const float* src = (g < 8) ? fd : fs;
  const int c0 = (g & 7) * 32;
  const int ccol0 = g * 32;
  const int tx = threadIdx.x;
  const int ty = threadIdx.y;
  const float* sp = src + ((long)b * 256 + c0) * 4096 + n0;
#pragma unroll
  for (int i = 0; i < 4; ++i) {
    int c = ty + i * 8;
    t[c][tx] = sp[(long)c * 4096 + tx];
  }
  __syncthreads();
  u16* op = out + ((long)b * 4096 + n0) * 512 + ccol0;
#pragma unroll
  for (int i = 0; i < 4; ++i) {
    int r = ty + i * 8;
    op[(long)r * 512 + tx] = f2b(t[tx][r]);
  }
}

// ---- bf16 NT GEMM: C[m,n] = sum_k A[m,k]*B[n,k] ----
// 128x128 tile, BK=64, 4 waves; global_load_lds(16B) staging with
// pre-swizzled SOURCE address (LDS dest linear, XOR-swizzled read).
// BIAS: 0 none, 2 bias[m]. POOL: also emit per-tile row sums.
template <typename OT, int BIAS, bool POOL>
__global__ __launch_bounds__(256) void gemm_nt(
    const u16* __restrict__ A, long sA, int lda,
    const u16* __restrict__ B, long sB, int ldb,
    OT* __restrict__ C, long sC, long sCs, int ldc,
    const float* __restrict__ bias, int Keff, int ksplit,
    float* __restrict__ poolpart) {
  __shared__ u16 ldsA[128 * 64];
  __shared__ u16 ldsB[128 * 64];
  const int z = blockIdx.z;
  const int bb = z / ksplit;
  const int ss = z - bb * ksplit;
  const int bm = blockIdx.x * 128;
  const int bn = blockIdx.y * 128;
  const u16* Ab = A + bb * sA + (long)ss * Keff + (long)bm * lda;
  const u16* Bb = B + bb * sB + (long)ss * Keff + (long)bn * ldb;
  const int tid = threadIdx.x;
  const int wid = tid >> 6;
  const int lane = tid & 63;
  const int wm = wid >> 1, wn = wid & 1;
  const int srow = tid >> 3;
  const int slot = tid & 7;

  fx4 acc[4][4] = {};
  for (int kt = 0; kt < Keff; kt += 64) {
#pragma unroll
    for (int i = 0; i < 4; ++i) {
      const int row = i * 32 + srow;
      const int kq = slot ^ (row & 7);
      GLOAD(Ab + (long)row * lda + kt + kq * 8, &ldsA[i * 2048 + wid * 512]);
      GLOAD(Bb + (long)row * ldb + kt + kq * 8, &ldsB[i * 2048 + wid * 512]);
    }
    __syncthreads();
#pragma unroll
    for (int ko = 0; ko < 2; ++ko) {
      bf8 af[4], bfr[4];
      const int kq = ko * 4 + (lane >> 4);
#pragma unroll
      for (int f = 0; f < 4; ++f) {
        const int ar = wm * 64 + f * 16 + (lane & 15);
        af[f] = *(const bf8*)&ldsA[ar * 64 + ((kq ^ (ar & 7)) * 8)];
        const int br = wn * 64 + f * 16 + (lane & 15);
        bfr[f] = *(const bf8*)&ldsB[br * 64 + ((kq ^ (br & 7)) * 8)];
      }
#pragma unroll
      for (int fm = 0; fm < 4; ++fm)
#pragma unroll
        for (int fn = 0; fn < 4; ++fn)
          acc[fm][fn] = __builtin_amdgcn_mfma_f32_16x16x32_bf16(af[fm], bfr[fn], acc[fm][fn], 0, 0, 0);
    }
    __syncthreads();
  }
  OT* Cb = C + bb * sC + ss * sCs;
  float pr[4][4];
  if (POOL) {
#pragma unroll
    for (int fm = 0; fm < 4; ++fm)
#pragma unroll
      for (int r = 0; r < 4; ++r) pr[fm][r] = 0.f;
  }
#pragma unroll
  for (int fm = 0; fm < 4; ++fm) {
    const int m0 = bm + wm * 64 + fm * 16 + ((lane >> 4) << 2);
#pragma unroll
    for (int fn = 0; fn < 4; ++fn) {
      const int n0 = bn + wn * 64 + fn * 16 + (lane & 15);
#pragma unroll
      for (int r = 0; r < 4; ++r) {
        float v = acc[fm][fn][r];
        if (BIAS == 2) v += bias[m0 + r];
        if constexpr (sizeof(OT) == 2) Cb[(long)(m0 + r) * ldc + n0] = (OT)f2b(v);
        else Cb[(long)(m0 + r) * ldc + n0] = v;
        if (POOL) pr[fm][r] += v;
      }
    }
  }
  if (POOL) {
#pragma unroll
    for (int fm = 0; fm < 4; ++fm)
#pragma unroll
      for (int r = 0; r < 4; ++r) {
        float s = pr[fm][r];
        s += __shfl_xor(s, 1); s += __shfl_xor(s, 2);
        s += __shfl_xor(s, 4); s += __shfl_xor(s, 8);
        if ((lane & 15) == 0) {
          const int o = bm + wm * 64 + fm * 16 + ((lane >> 4) << 2) + r;
          poolpart[(long)(blockIdx.y * 2 + wn) * 2048 + bb * 256 + o] = s;
        }
      }
  }
}

// ---- depthwise 3x3 SAME, [B,N,C] bf16 layout ----
__global__ __launch_bounds__(256) void dwconv3x3(const u16* __restrict__ x,
                                                 const float* __restrict__ wdw,
                                                 u16* __restrict__ y) {
  __shared__ float w[9][256];
  const int t = threadIdx.x;
  for (int i = t; i < 2304; i += 256) w[i % 9][i / 9] = wdw[i];
  __syncthreads();
  const int nb = blockIdx.x;
  const int b = nb >> 9;
  const int n0 = (nb & 511) << 3;
  const int tn = t >> 5;
  const int tc = (t & 31) << 3;
  const int n = n0 + tn;
  const int hh = n >> 6, ww2 = n & 63;
  const u16* base = x + ((long)b << 20);
  float acc[8] = {0.f, 0.f, 0.f, 0.f, 0.f, 0.f, 0.f, 0.f};
#pragma unroll
  for (int ky = 0; ky < 3; ++ky) {
    const int hy = hh + ky - 1;
    if ((unsigned)hy >= 64u) continue;
#pragma unroll
    for (int kx = 0; kx < 3; ++kx) {
      const int wx = ww2 + kx - 1;
      if ((unsigned)wx >= 64u) continue;
      const s8v v = *(const s8v*)&base[(((hy << 6) + wx) << 8) + tc];
      const int kk = ky * 3 + kx;
      const fx4 wa = *(const fx4*)&w[kk][tc];
      const fx4 wb = *(const fx4*)&w[kk][tc + 4];
#pragma unroll
      for (int j = 0; j < 4; ++j) {
        acc[j] += wa[j] * b2f((u16)v[j]);
        acc[4 + j] += wb[j] * b2f((u16)v[4 + j]);
      }
    }
  }
  s8v o;
#pragma unroll
  for (int j = 0; j < 8; ++j) o[j] = (short)f2b(acc[j]);
  *(s8v*)&y[((long)b << 20) + ((long)n << 8) + tc] = o;
}

// ---- bf16 transpose: xt [B,4096,256] -> xtT [B,256,4096] ----
__global__ void btrans(const u16* __restrict__ x, u16* __restrict__ y) {
  __shared__ u16 t[32][34];
  const int b = blockIdx.z;
  const int n0 = blockIdx.x * 32;
  const int c0 = blockIdx.y * 32;
  const int tx = threadIdx.x, ty = threadIdx.y;
  const u16* sp = x + (long)b * 1048576 + (long)n0 * 256 + c0;
#pragma unroll
  for (int j = 0; j < 4; ++j) {
    int i = ty + j * 8;
    t[i][tx] = sp[(long)i * 256 + tx];
  }
  __syncthreads();
  u16* op = y + (long)b * 1048576 + (long)c0 * 4096 + n0;
#pragma unroll
  for (int j = 0; j < 4; ++j) {
    int r = ty + j * 8;
    op[(long)r * 4096 + tx] = t[tx][r];
  }
}

// ---- sum Gram split-K partials -> hi/lo bf16 G2 [B,256,512] ----
__global__ __launch_bounds__(256) void gsplit(const float* __restrict__ part,
                                              u16* __restrict__ G2) {
  const int i4 = (blockIdx.x * 256 + threadIdx.x) * 4;    // over 524288
  fx4 s = {0.f, 0.f, 0.f, 0.f};
#pragma unroll
  for (int ss = 0; ss < 8; ++ss) s += *(const fx4*)(part + (long)ss * 524288 + i4);
  const int b = i4 >> 16, rem = i4 & 65535, e = rem >> 8, c0 = rem & 255;
  u16* d = G2 + (long)b * 131072 + (long)e * 512 + c0;
  s4v hi, lo;
#pragma unroll
  for (int j = 0; j < 4; ++j) {
    u16 h = f2b(s[j]);
    hi[j] = (short)h;
    lo[j] = (short)f2b(s[j] - b2f(h));
  }
  *(s4v*)d = hi;
  *(s4v*)(d + 256) = lo;
}

// ---- split SS(q-part) -> hi/lo bf16 S2, and diag norms -> rinv ----
__global__ __launch_bounds__(256) void ssplit_diag(const float* __restrict__ SS,
                                                   const float* __restrict__ Wq,
                                                   const float* __restrict__ Wk,
                                                   u16* __restrict__ S2,
                                                   float* __restrict__ rinv) {
  const int wid = threadIdx.x >> 6, lane = threadIdx.x & 63;
  const int gid = blockIdx.x * 4 + wid;     // 0..4095
  const int b = gid >> 9, row = gid & 511;
  const float* ssrow = SS + (long)b * 131072 + (long)row * 256;
  const float* wrow = (row < 256) ? (Wq + row * 256) : (Wk + (row - 256) * 256);
  const fx4 sv = ((const fx4*)ssrow)[lane];
  const fx4 wv = ((const fx4*)wrow)[lane];
  float dot = sv[0] * wv[0] + sv[1] * wv[1] + sv[2] * wv[2] + sv[3] * wv[3];
#pragma unroll
  for (int o = 32; o > 0; o >>= 1) dot += __shfl_xor(dot, o);
  if (lane == 0)
    rinv[b * 512 + row] = 1.f / fmaxf(sqrtf(fmaxf(dot, 0.f)), 1e-12f);
  if (row < 256) {
    u16* d = S2 + (long)b * 131072 + (long)row * 512 + lane * 4;
    s4v hi, lo;
#pragma unroll
    for (int j = 0; j < 4; ++j) {
      u16 h = f2b(sv[j]);
      hi[j] = (short)h;
      lo[j] = (short)f2b(sv[j] - b2f(h));
    }
    *(s4v*)d = hi;
    *(s4v*)(d + 256) = lo;
  }
}

// ---- apply norm scales + row softmax over d -> bf16 attn ----
__global__ __launch_bounds__(256) void softmax_g(const float* __restrict__ araw,
                                                 const float* __restrict__ rinv,
                                                 u16* __restrict__ out) {
  const int wid = threadIdx.x >> 6, lane = threadIdx.x & 63;
  const long row = (long)blockIdx.x * 4 + wid;   // b*256 + c
  const int b = (int)(row >> 8);
  const int c = (int)(row & 255);
  fx4 v = ((const fx4*)(araw + row * 256))[lane];
  const float rk = rinv[b * 512 + 256 + c];
  const fx4 rq = *(const fx4*)&rinv[b * 512 + lane * 4];
  v[0] *= rk * rq[0]; v[1] *= rk * rq[1]; v[2] *= rk * rq[2]; v[3] *= rk * rq[3];
  float m = fmaxf(fmaxf(v[0], v[1]), fmaxf(v[2], v[3]));
#pragma unroll
  for (int o = 32; o > 0; o >>= 1) m = fmaxf(m, __shfl_xor(m, o));
  float e0 = __expf(v[0] - m), e1 = __expf(v[1] - m);
  float e2 = __expf(v[2] - m), e3 = __expf(v[3] - m);
  float s4 = e0 + e1 + e2 + e3;
#pragma unroll
  for (int o = 32; o > 0; o >>= 1) s4 += __shfl_xor(s4, o);
  const float inv = 1.f / s4;
  u16* op = out + row * 256 + lane * 4;
  op[0] = f2b(e0 * inv); op[1] = f2b(e1 * inv);
  op[2] = f2b(e2 * inv); op[3] = f2b(e3 * inv);
}

// ---- SE gates: sum pooled partials + 2-layer MLP ----
__global__ __launch_bounds__(256) void se_gates(const float* __restrict__ poolpart,
                                                const float* __restrict__ w1d, const float* __restrict__ w2d,
                                                const float* __restrict__ w1s, const float* __restrict__ w2s,
                                                float* __restrict__ gd, float* __restrict__ gs) {
  const int b = blockIdx.x;
  const int t = threadIdx.x;
  __shared__ float p[256], hd[16], hs[16];
  float s = 0.f;
#pragma unroll 8
  for (int sl = 0; sl < 64; ++sl) s += poolpart[(long)sl * 2048 + b * 256 + t];
  p[t] = s * (1.f / 4096.f);
  __syncthreads();
  if (t < 16) {
    float ad = 0.f, as2 = 0.f;
    for (int j = 0; j < 256; ++j) {
      ad += w1d[t * 256 + j] * p[j];
      as2 += w1s[t * 256 + j] * p[j];
    }
    hd[t] = fmaxf(ad, 0.f);
    hs[t] = fmaxf(as2, 0.f);
  }
  __syncthreads();
  float ad = 0.f, as2 = 0.f;
#pragma unroll
  for (int r = 0; r < 16; ++r) {
    ad += w2d[t * 16 + r] * hd[r];
    as2 += w2s[t * 16 + r] * hs[r];
  }
  gd[b * 256 + t] = 1.f / (1.f + __expf(-ad));
  gs[b * 256 + t] = 1.f / (1.f + __expf(-as2));
}

// ---- final: out = outc(bf16) * gate + residual, both branches ----
__global__ __launch_bounds__(256) void fuse_out(const u16* __restrict__ oc,
                                                const float* __restrict__ gd, const float* __restrict__ gs,
                                                const float* __restrict__ fd, const float* __restrict__ fs,
                                                float* __restrict__ od, float* __restrict__ os) {
  const long i = ((long)blockIdx.x * 256 + threadIdx.x) * 8;
  const long bc = i >> 12;
  const float gdv = gd[bc], gsv = gs[bc];
  const s8v c8 = *(const s8v*)&oc[i];
  const fx4 a0 = *(const fx4*)(fd + i), a1 = *(const fx4*)(fd + i + 4);
  const fx4 s0 = *(const fx4*)(fs + i), s1 = *(const fx4*)(fs + i + 4);
  fx4 d0, d1, e0, e1;
#pragma unroll
  for (int j = 0; j < 4; ++j) {
    const float cl = b2f((u16)c8[j]);
    const float ch = b2f((u16)c8[4 + j]);
    d0[j] = cl * gdv + a0[j]; d1[j] = ch * gdv + a1[j];
    e0[j] = cl * gsv + s0[j]; e1[j] = ch * gsv + s1[j];
  }
  *(fx4*)(od + i) = d0; *(fx4*)(od + i + 4) = d1;
  *(fx4*)(os + i) = e0; *(fx4*)(os + i + 4) = e1;
}

extern "C" void kernel_launch(void* const* d_in, const int* in_sizes, int n_in,
                              void* d_out, int out_size, void* d_ws, size_t ws_size,
                              hipStream_t stream) {
  const float* fd  = (const float*)d_in[0];
  const float* fs  = (const float*)d_in[1];
  const float* W0  = (const float*)d_in[2];
  const float* Wdw = (const float*)d_in[3];
  const float* Wq  = (const float*)d_in[4];
  const float* Wk  = (const float*)d_in[5];
  const float* Wv  = (const float*)d_in[6];
  const float* Wp  = (const float*)d_in[7];
  const float* bp  = (const float*)d_in[8];
  const float* Wsp = (const float*)d_in[9];
  const float* w1d = (const float*)d_in[10];
  const float* w2d = (const float*)d_in[11];
  const float* w1s = (const float*)d_in[12];
  const float* w2s = (const float*)d_in[13];

  char* ws = (char*)d_ws;
  u16* catb   = (u16*)(ws + 0);            // [B,N,512] bf16 32MB; dead after conv0
  u16* xtT    = (u16*)(ws + 0);            // [B,256,4096] bf16 16MB (reuses catb)
  u16* x0b    = (u16*)(ws + 33554432);     // [B,N,256] bf16 16MB; dead after dwconv
  u16* outcb  = x0b;                       // [B,256,N] bf16 16MB (reuse)
  u16* xtb    = (u16*)(ws + 50331648);     // [B,N,256] bf16 16MB; live to final gemm
  float* part = (float*)(ws + 67108864);   // [8][B,256,256] fp32 16.7MB; dead after gsplit
  u16* G2     = (u16*)(ws + 83886080);     // [B,256,512] bf16 hi|lo 2.1MB
  float* SS   = (float*)(ws + 85983232);   // [B,512,256] fp32 4.2MB
  u16* S2     = (u16*)(ws + 90177536);     // [B,256,512] bf16 hi|lo 2.1MB
  float* araw = (float*)(ws + 92274688);   // [B,256,256] fp32 2.1MB
  u16* attnb  = (u16*)(ws + 94371840);     // [B,256,256] bf16 1MB
  u16* m1t    = (u16*)(ws + 95420416);     // [B,256,256] bf16 1MB  (M1^T[e,c])
  u16* wfin   = (u16*)(ws + 96468992);     // [B,256,256] bf16 1MB  (Wfin[o,e])
  u16* w0b    = (u16*)(ws + 97517568);     // 131072 el
  u16* wqk2   = (u16*)(ws + 97779712);     // [512,512] bf16
  u16* wvtb   = (u16*)(ws + 98304000);     // [256,256] bf16 (WvT)
  u16* wcb    = (u16*)(ws + 98435072);     // [256,256] bf16 (Wsp@Wp)
  float* bcb  = (float*)(ws + 98566144);   // 256
  float* rinv = (float*)(ws + 98567168);   // [B,512]
  float* poolpart = (float*)(ws + 98583552); // [64][B,256] fp32
  float* gdp  = (float*)(ws + 99108864);
  float* gsp  = (float*)(ws + 99117056);
  float* od  = (float*)d_out;
  float* osg = od + 8388608;

  prep<<<dim3(2048, 3), 256, 0, stream>>>(W0, Wq, Wk, Wv, w0b, wqk2, wvtb);
  wcmul<<<256, 256, 0, stream>>>(Wsp, Wp, bp, wcb, bcb);
  pack_cat<<<dim3(128, 16, 8), dim3(32, 8), 0, stream>>>(fd, fs, catb);
  // conv0: x0[b,n,o] = sum_c cat[b,n,c] W0[o,c]   M=4096 N=256 K=512
  gemm_nt<u16, 0, false><<<dim3(32, 2, 8), 256, 0, stream>>>(
      catb, 2097152, 512, w0b, 0, 512, x0b, 1048576, 0, 256, nullptr, 512, 1, nullptr);
  dwconv3x3<<<4096, 256, 0, stream>>>(x0b, Wdw, xtb);
  btrans<<<dim3(128, 8, 8), dim3(32, 8), 0, stream>>>(xtb, xtT);
  // Gram: G[b,c,e] = sum_n xtT[b,c,n] xtT[b,e,n]   M=256 N=256 K=4096, split-K x8
  gemm_nt<float, 0, false><<<dim3(2, 2, 64), 256, 0, stream>>>(
      xtT, 1048576, 4096, xtT, 1048576, 4096,
      part, 65536, 524288, 256, nullptr, 512, 8, nullptr);
  gsplit<<<512, 256, 0, stream>>>(part, G2);
  // SS[b,row,e] = (Wqk @ G)[row,e]: A=[Wq|Wq;Wk|Wk], B=G2 hi|lo   M=512 N=256 K=512
  gemm_nt<float, 0, false><<<dim3(4, 2, 8), 256, 0, stream>>>(
      wqk2, 0, 512, G2, 131072, 512, SS, 131072, 0, 256, nullptr, 512, 1, nullptr);
  ssplit_diag<<<1024, 256, 0, stream>>>(SS, Wq, Wk, S2, rinv);
  // araw[b,c,d] = (Wk G Wq^T)[c,d]: A=[Wk|Wk], B=S2 hi|lo   M=256 N=256 K=512
  gemm_nt<float, 0, false><<<dim3(2, 2, 8), 256, 0, stream>>>(
      wqk2 + 131072, 0, 512, S2, 131072, 512, araw, 65536, 0, 256, nullptr, 512, 1, nullptr);
  softmax_g<<<512, 256, 0, stream>>>(araw, rinv, attnb);
  // m1t[b,e,c] = sum_d WvT[e,d] attn[b,c,d]   M=256 N=256 K=256
  gemm_nt<u16, 0, false><<<dim3(2, 2, 8), 256, 0, stream>>>(
      wvtb, 0, 256, attnb, 65536, 256, m1t, 65536, 0, 256, nullptr, 256, 1, nullptr);
  // wfin[b,o,e] = sum_c Wc[o,c] m1t[b,e,c]   M=256 N=256 K=256
  gemm_nt<u16, 0, false><<<dim3(2, 2, 8), 256, 0, stream>>>(
      wcb, 0, 256, m1t, 65536, 256, wfin, 65536, 0, 256, nullptr, 256, 1, nullptr);
  // outc[b,o,n] = sum_e wfin[b,o,e] xt[b,n,e] + bc[o]   M=256 N=4096 K=256, +pool
  gemm_nt<u16, 2, true><<<dim3(2, 32, 8), 256, 0, stream>>>(
      wfin, 65536, 256, xtb, 1048576, 256, outcb, 1048576, 0, 4096, bcb, 256, 1, poolpart);
  se_gates<<<8, 256, 0, stream>>>(poolpart, w1d, w2d, w1s, w2s, gdp, gsp);
  fuse_out<<<4096, 256, 0, stream>>>(outcb, gdp, gsp, fd, fs, od, osg);
}